// Round 1
// baseline (62.647 us; speedup 1.0000x reference)
//
#include <hip/hip_runtime.h>

// Problem constants (fixed by the reference):
//   x: (B=256, T=32768, C=10) fp32, window KW=64 along T, stride KW.
//   out[b,t,c] = sum_{k,i} x[b, t*64+k, i] * w[k], identical for all c.
//   w = softmax(p5*i + p6*i*i), i = 1..64.
#define KW 64
#define C 10
#define B_DIM 256
#define T_DIM 32768
#define NWIN (T_DIM / KW)                 // 512
#define NWINDOWS (B_DIM * NWIN)           // 131072
#define WIN_FLOATS (KW * C)               // 640 contiguous floats per window
#define WIN_VEC (WIN_FLOATS / 4)          // 160 float4 per window
#define LANES_PER_WIN 16
#define GROUPS_PER_BLOCK 16               // 256 threads / 16 lanes
#define NCHUNKS (NWINDOWS / GROUPS_PER_BLOCK)  // 8192 block-iterations

__global__ __launch_bounds__(256) void conv1d_wsum_kernel(
    const float* __restrict__ x,
    const float* __restrict__ p5p,
    const float* __restrict__ p6p,
    float* __restrict__ out) {
  __shared__ float w_lds[KW];

  const int tid = threadIdx.x;

  // ---- softmax over the 64 lag-weights, computed by wave 0 ----
  if (tid < 64) {
    float fi = (float)(tid + 1);
    float ll = p5p[0] * fi + p6p[0] * fi * fi;
    float m = ll;
#pragma unroll
    for (int off = 32; off >= 1; off >>= 1) m = fmaxf(m, __shfl_xor(m, off));
    float e = expf(ll - m);
    float s = e;
#pragma unroll
    for (int off = 32; off >= 1; off >>= 1) s += __shfl_xor(s, off);
    w_lds[tid] = e / s;
  }
  __syncthreads();

  const int l = tid & (LANES_PER_WIN - 1);  // lane within window group
  const int g = tid >> 4;                   // window group within block

  // ---- hoist this lane's 40 element-weights into registers ----
  // lane l covers float4 indices f = l + 16*j (j=0..9) of its window;
  // element e = 4*f + m has weight w[e/10].
  float4 wr[10];
#pragma unroll
  for (int j = 0; j < 10; ++j) {
    int e = 4 * (l + LANES_PER_WIN * j);
    wr[j].x = w_lds[(e + 0) / 10];
    wr[j].y = w_lds[(e + 1) / 10];
    wr[j].z = w_lds[(e + 2) / 10];
    wr[j].w = w_lds[(e + 3) / 10];
  }

  const float4* __restrict__ x4 = (const float4*)x;

  // ---- stream windows: 16 windows per block per chunk, grid-stride ----
  for (int chunk = blockIdx.x; chunk < NCHUNKS; chunk += gridDim.x) {
    const long long w = (long long)chunk * GROUPS_PER_BLOCK + g;
    const float4* base = x4 + w * (long long)WIN_VEC + l;

    float acc = 0.0f;
#pragma unroll
    for (int j = 0; j < 10; ++j) {
      float4 v = base[LANES_PER_WIN * j];
      acc = fmaf(v.x, wr[j].x, acc);
      acc = fmaf(v.y, wr[j].y, acc);
      acc = fmaf(v.z, wr[j].z, acc);
      acc = fmaf(v.w, wr[j].w, acc);
    }

    // butterfly reduce within the 16-lane group (xor offsets < 16 stay in-group)
#pragma unroll
    for (int off = 8; off >= 1; off >>= 1) acc += __shfl_xor(acc, off);

    // all 16 lanes hold the window sum; lanes 0..9 write the 10 channels
    if (l < C) out[w * C + l] = acc;
  }
}

extern "C" void kernel_launch(void* const* d_in, const int* in_sizes, int n_in,
                              void* d_out, int out_size, void* d_ws, size_t ws_size,
                              hipStream_t stream) {
  const float* x  = (const float*)d_in[0];
  const float* p5 = (const float*)d_in[1];
  const float* p6 = (const float*)d_in[2];
  float* out = (float*)d_out;

  dim3 grid(2048);
  dim3 block(256);
  conv1d_wsum_kernel<<<grid, block, 0, stream>>>(x, p5, p6, out);
}

// Round 3
// 55.730 us; speedup vs baseline: 1.1241x; 1.1241x over previous
//
#include <hip/hip_runtime.h>

// Problem constants (fixed by the reference):
//   x: (B=256, T=32768, C=10) fp32, window KW=64 along T, stride KW.
//   out[b,t,c] = sum_{k,i} x[b, t*64+k, i] * w[k], identical for all c.
//   w = softmax(p5*i + p6*i*i), i = 1..64.
#define KW 64
#define C 10
#define B_DIM 256
#define T_DIM 32768
#define NWIN (T_DIM / KW)                 // 512
#define NWINDOWS (B_DIM * NWIN)           // 131072
#define WIN_FLOATS (KW * C)               // 640 contiguous floats per window
#define WIN_VEC (WIN_FLOATS / 4)          // 160 float4 per window
#define LANES_PER_WIN 16
#define GROUPS_PER_BLOCK 16               // 256 threads / 16 lanes
#define NCHUNKS (NWINDOWS / GROUPS_PER_BLOCK)  // 8192 blocks, 1 chunk each

typedef float f4 __attribute__((ext_vector_type(4)));  // native vec for nt-load

__global__ __launch_bounds__(256) void conv1d_wsum_kernel(
    const float* __restrict__ x,
    const float* __restrict__ p5p,
    const float* __restrict__ p6p,
    float* __restrict__ out) {
  __shared__ float w_lds[KW];

  const int tid = threadIdx.x;

  // ---- softmax over the 64 lag-weights, computed by wave 0 ----
  if (tid < 64) {
    float fi = (float)(tid + 1);
    float ll = p5p[0] * fi + p6p[0] * fi * fi;
    float m = ll;
#pragma unroll
    for (int off = 32; off >= 1; off >>= 1) m = fmaxf(m, __shfl_xor(m, off));
    float e = expf(ll - m);
    float s = e;
#pragma unroll
    for (int off = 32; off >= 1; off >>= 1) s += __shfl_xor(s, off);
    w_lds[tid] = e / s;
  }
  __syncthreads();

  const int l = tid & (LANES_PER_WIN - 1);  // lane within window group
  const int g = tid >> 4;                   // window group within block

  // ---- hoist this lane's 40 element-weights into registers ----
  // lane l covers float4 indices f = l + 16*j (j=0..9) of its window;
  // element e = 4*f + m has weight w[e/10].
  f4 wr[10];
#pragma unroll
  for (int j = 0; j < 10; ++j) {
    int e = 4 * (l + LANES_PER_WIN * j);
    wr[j].x = w_lds[(e + 0) / 10];
    wr[j].y = w_lds[(e + 1) / 10];
    wr[j].z = w_lds[(e + 2) / 10];
    wr[j].w = w_lds[(e + 3) / 10];
  }

  const f4* __restrict__ x4 = (const f4*)x;

  // ---- one 16-window chunk per block; nontemporal streaming loads ----
  const int chunk = blockIdx.x;  // grid is exactly NCHUNKS
  const long long w = (long long)chunk * GROUPS_PER_BLOCK + g;
  const f4* base = x4 + w * (long long)WIN_VEC + l;

  float acc = 0.0f;
#pragma unroll
  for (int j = 0; j < 10; ++j) {
    f4 v = __builtin_nontemporal_load(base + LANES_PER_WIN * j);
    acc = fmaf(v.x, wr[j].x, acc);
    acc = fmaf(v.y, wr[j].y, acc);
    acc = fmaf(v.z, wr[j].z, acc);
    acc = fmaf(v.w, wr[j].w, acc);
  }

  // butterfly reduce within the 16-lane group (xor offsets < 16 stay in-group)
#pragma unroll
  for (int off = 8; off >= 1; off >>= 1) acc += __shfl_xor(acc, off);

  // all 16 lanes hold the window sum; lanes 0..9 write the 10 channels
  if (l < C) __builtin_nontemporal_store(acc, &out[w * C + l]);
}

extern "C" void kernel_launch(void* const* d_in, const int* in_sizes, int n_in,
                              void* d_out, int out_size, void* d_ws, size_t ws_size,
                              hipStream_t stream) {
  const float* x  = (const float*)d_in[0];
  const float* p5 = (const float*)d_in[1];
  const float* p6 = (const float*)d_in[2];
  float* out = (float*)d_out;

  dim3 grid(NCHUNKS);
  dim3 block(256);
  conv1d_wsum_kernel<<<grid, block, 0, stream>>>(x, p5, p6, out);
}